// Round 1
// baseline (2822.517 us; speedup 1.0000x reference)
//
#include <hip/hip_runtime.h>
#include <hip/hip_bf16.h>
#include <hip/hip_cooperative_groups.h>

namespace cg = cooperative_groups;

#define DEV __device__ __forceinline__

typedef unsigned short u16;
typedef short bf16x8_t __attribute__((ext_vector_type(8)));
typedef float f32x4_t __attribute__((ext_vector_type(4)));

// Model dims
// B=256 H=1024 F=512 P=66 T_IN=10 T_OUT=25, gates 4H=4096
// enc K = F+H = 1536 ; dec K (lin fused) = H+H = 2048
constexpr int NBLK = 256;
constexpr int NTHR = 512;
constexpr int NT_ALL = NBLK * NTHR; // 131072

struct Params {
  const float *x, *z, *resid, *tf_w, *tf_b;
  const float *e_wih, *e_whh, *e_bih, *e_bhh;
  const float *p_wih, *p_whh, *p_bih, *p_bhh;
  const float *d_wih, *d_whh, *d_bih, *d_bhh;
  const float *lin_w, *lin_b, *tp_w, *tp_b;
  u16 *Wenc, *Wencp, *Wdec, *wihP, *linT, *tpw;
  float *bias_e, *bias_ep, *bias_d;
  u16 *xf, *zf;
  u16 *he0, *he1, *hp0, *hp1, *hd0, *hd1;
  float *c_e, *c_ep;
  u16 *atth, *cat, *hs;
  float *out;
};

DEV float b2f(u16 v) { unsigned u = ((unsigned)v) << 16; float f; __builtin_memcpy(&f, &u, 4); return f; }
DEV u16 f2b(float f) {
  unsigned u; __builtin_memcpy(&u, &f, 4);
  unsigned r = u + 0x7fffu + ((u >> 16) & 1u);   // RNE
  return (u16)(r >> 16);
}
DEV unsigned pk2(float a, float b) { return (unsigned)f2b(a) | ((unsigned)f2b(b) << 16); }
DEV uint4 cvt8(const float* s) {
  float4 a = *(const float4*)s;
  float4 b = *(const float4*)(s + 4);
  uint4 r;
  r.x = pk2(a.x, a.y); r.y = pk2(a.z, a.w);
  r.z = pk2(b.x, b.y); r.w = pk2(b.z, b.w);
  return r;
}
DEV float sigm(float x) { return 1.0f / (1.0f + __expf(-x)); }
DEV f32x4_t fzero4() { f32x4_t v = {0.f, 0.f, 0.f, 0.f}; return v; }

DEV void gll16(const void* g, void* l) {
  __builtin_amdgcn_global_load_lds(
      (const __attribute__((address_space(1))) void*)g,
      (__attribute__((address_space(3))) void*)l, 16, 0, 0);
}

// ---------------- 64x64-tile bf16 GEMM, K multiple of 64 -------------------
// A rows m0..m0+63 come from xa (k < xcols, stride ldx) then ha (stride ldh).
// B rows (output cols) n0..n0+63 from wsrc (stride ldw) -- wsrc holds W[n][k],
// which is B^T, matching the MFMA B-fragment layout directly.
// LDS: sm[0..16K) = A dbuf, sm[16K..32K) = B dbuf. Source-side XOR swizzle
// (16B unit ^= row&7) + same XOR on ds_read -> conflict-free b128 reads.
DEV void gemm64(const u16* __restrict__ xa, int ldx, int xcols,
                const u16* __restrict__ ha, int ldh,
                const u16* __restrict__ wsrc, int ldw, int K,
                int m0, int n0, int tid, char* sm, f32x4_t acc[2]) {
  char* lA = sm;
  char* lB = sm + 16384;
  const int NK = K >> 6;
  const int row = tid >> 3, uu = tid & 7;
  const int usw = uu ^ (row & 7);
  const int wv = tid >> 6;
  char* la_base = lA + (wv << 10);
  char* lb_base = lB + (wv << 10);

  auto stage = [&](int ks) {
    const int k0 = ks << 6;
    const u16* ga;
    if (k0 < xcols) ga = xa + (size_t)(m0 + row) * ldx + (k0 + usw * 8);
    else            ga = ha + (size_t)(m0 + row) * ldh + (k0 - xcols + usw * 8);
    const u16* gb = wsrc + (size_t)(n0 + row) * ldw + (k0 + usw * 8);
    const int sel = (ks & 1) << 13;
    gll16(ga, la_base + sel);
    gll16(gb, lb_base + sel);
  };

  const int l = tid & 63, l15 = l & 15, lhi = l >> 4;
  const int wr = wv >> 1, wc = wv & 1;       // 4x2 wave grid, wave tile 16x32
  const int rA = wr * 16 + l15;
  const int aoff0 = rA * 128 + (((lhi)     ^ (rA & 7)) << 4);
  const int aoff1 = rA * 128 + (((lhi + 4) ^ (rA & 7)) << 4);
  const int nB0 = wc * 32 + l15;
  const int nB1 = nB0 + 16;
  const int boff00 = nB0 * 128 + (((lhi)     ^ (nB0 & 7)) << 4);
  const int boff01 = nB0 * 128 + (((lhi + 4) ^ (nB0 & 7)) << 4);
  const int boff10 = nB1 * 128 + (((lhi)     ^ (nB1 & 7)) << 4);
  const int boff11 = nB1 * 128 + (((lhi + 4) ^ (nB1 & 7)) << 4);

  stage(0);
  for (int ks = 0; ks < NK; ++ks) {
    __syncthreads();                    // staging of buf[ks&1] complete
    if (ks + 1 < NK) stage(ks + 1);     // prefetch overlaps compute
    const char* A  = lA + ((ks & 1) << 13);
    const char* Bb = lB + ((ks & 1) << 13);
    bf16x8_t a0  = *(const bf16x8_t*)(A + aoff0);
    bf16x8_t a1  = *(const bf16x8_t*)(A + aoff1);
    bf16x8_t b00 = *(const bf16x8_t*)(Bb + boff00);
    bf16x8_t b01 = *(const bf16x8_t*)(Bb + boff01);
    bf16x8_t b10 = *(const bf16x8_t*)(Bb + boff10);
    bf16x8_t b11 = *(const bf16x8_t*)(Bb + boff11);
    acc[0] = __builtin_amdgcn_mfma_f32_16x16x32_bf16(a0, b00, acc[0], 0, 0, 0);
    acc[0] = __builtin_amdgcn_mfma_f32_16x16x32_bf16(a1, b01, acc[0], 0, 0, 0);
    acc[1] = __builtin_amdgcn_mfma_f32_16x16x32_bf16(a0, b10, acc[1], 0, 0, 0);
    acc[1] = __builtin_amdgcn_mfma_f32_16x16x32_bf16(a1, b11, acc[1], 0, 0, 0);
  }
  __syncthreads();                      // all LDS reads done before reuse
}

// ----------------- LSTM pointwise epilogue (gate-interleaved) --------------
// Gate columns n' = 4*j + {i,f,g,o}; tile owns 16 consecutive j cells.
DEV void lstm_ep(const f32x4_t acc[2], int tid, char* sm,
                 const float* __restrict__ bias, float* __restrict__ cbuf,
                 u16* __restrict__ hw, u16* __restrict__ catw,
                 u16* __restrict__ hsw, int m0, int n0) {
  float* gl = (float*)sm;               // [64][68] f32 overlay on staging LDS
  const int l = tid & 63, l15 = l & 15, lhi = l >> 4;
  const int wv = tid >> 6, wr = wv >> 1, wc = wv & 1;
#pragma unroll
  for (int j = 0; j < 2; ++j)
#pragma unroll
    for (int qq = 0; qq < 4; ++qq)
      gl[(wr * 16 + lhi * 4 + qq) * 68 + wc * 32 + j * 16 + l15] = acc[j][qq];
  __syncthreads();
#pragma unroll
  for (int it = 0; it < 2; ++it) {
    int idx = it * 512 + tid;           // 1024 items: 64 rows x 16 j
    int r = idx >> 4, jj = idx & 15;
    f32x4_t g4 = *(const f32x4_t*)(gl + r * 68 + jj * 4);
    f32x4_t b4 = *(const f32x4_t*)(bias + n0 + jj * 4);
    float ig = sigm(g4[0] + b4[0]);
    float fg = sigm(g4[1] + b4[1]);
    float g_ = tanhf(g4[2] + b4[2]);
    float og = sigm(g4[3] + b4[3]);
    size_t off = (size_t)(m0 + r) * 1024 + (n0 >> 2) + jj;
    float cn = fg * cbuf[off] + ig * g_;
    float hn = og * tanhf(cn);
    cbuf[off] = cn;
    u16 hb = f2b(hn);
    hw[off] = hb;
    if (catw) catw[off] = hb;
    if (hsw)  hsw[off]  = hb;
  }
  __syncthreads();                      // protect gl before next staging
}

DEV void wx_store(const f32x4_t acc[2], int tid, u16* __restrict__ Wdec,
                  int m0, int n0) {
  const int l = tid & 63, l15 = l & 15, lhi = l >> 4;
  const int wv = tid >> 6, wr = wv >> 1, wc = wv & 1;
#pragma unroll
  for (int j = 0; j < 2; ++j)
#pragma unroll
    for (int qq = 0; qq < 4; ++qq) {
      int r = m0 + wr * 16 + lhi * 4 + qq;
      int c = n0 + wc * 32 + j * 16 + l15;
      Wdec[(size_t)r * 2048 + c] = f2b(acc[j][qq]);
    }
}

// --------------------------- phase 0a: conversions -------------------------
DEV void phase0a(const Params& p, int gtid) {
  // enc / encp combined weights, gate-interleaved rows: n' = 4j+g
  for (int g = gtid; g < 786432; g += NT_ALL) {     // 4096 x 192 units
    int row = g / 192;
    int u = g - row * 192;
    int k = u * 8;
    int nsrc = (row & 3) * 1024 + (row >> 2);
    const float* s1 = (k < 512) ? (p.e_wih + (size_t)nsrc * 512 + k)
                                : (p.e_whh + (size_t)nsrc * 1024 + (k - 512));
    ((uint4*)p.Wenc)[g] = cvt8(s1);
    const float* s2 = (k < 512) ? (p.p_wih + (size_t)nsrc * 512 + k)
                                : (p.p_whh + (size_t)nsrc * 1024 + (k - 512));
    ((uint4*)p.Wencp)[g] = cvt8(s2);
  }
  // dec whh -> Wdec[:,1024:2048]
  for (int g = gtid; g < 524288; g += NT_ALL) {     // 4096 x 128 units
    int row = g >> 7, u = g & 127;
    int nsrc = (row & 3) * 1024 + (row >> 2);
    ((uint4*)p.Wdec)[row * 256 + 128 + u] = cvt8(p.d_whh + (size_t)nsrc * 1024 + u * 8);
  }
  // dec wih (gate-permuted) to bf16 scratch
  for (int g = gtid; g < 262144; g += NT_ALL) {     // 4096 x 64 units
    int row = g >> 6, u = g & 63;
    int nsrc = (row & 3) * 1024 + (row >> 2);
    ((uint4*)p.wihP)[g] = cvt8(p.d_wih + (size_t)nsrc * 512 + u * 8);
  }
  // lin_w transpose -> linT[h][f] (coalesced reads, scattered 2B writes)
  for (int g = gtid; g < 524288; g += NT_ALL) {
    int f = g >> 10, h = g & 1023;
    p.linT[(size_t)h * 512 + f] = f2b(p.lin_w[g]);
  }
  // tp_w bf16
  for (int g = gtid; g < 8448; g += NT_ALL)
    ((uint4*)p.tpw)[g] = cvt8(p.tp_w + g * 8);
  // biases (dec bias includes wih @ lin_b from the fused lin layer)
  for (int g = gtid; g < 4096; g += NT_ALL) {
    int nsrc = (g & 3) * 1024 + (g >> 2);
    p.bias_e[g]  = p.e_bih[nsrc] + p.e_bhh[nsrc];
    p.bias_ep[g] = p.p_bih[nsrc] + p.p_bhh[nsrc];
    float s = p.d_bih[nsrc] + p.d_bhh[nsrc];
    const float* wr_ = p.d_wih + (size_t)nsrc * 512;
    for (int f = 0; f < 512; ++f) s += wr_[f] * p.lin_b[f];
    p.bias_d[g] = s;
  }
  // ToFeature for x and z: xf[t][b][n]
  for (int g = gtid; g < 1310720; g += NT_ALL) {
    int n = g & 511, bt = g >> 9;
    int b = bt & 255, t = bt >> 8;
    const float* xr = p.x + ((size_t)b * 10 + t) * 66;
    const float* zr = p.z + ((size_t)b * 10 + t) * 66;
    const float* wrow = p.tf_w + (size_t)n * 66;
    float s1 = p.tf_b[n], s2 = s1;
    for (int qi = 0; qi < 66; ++qi) { float w_ = wrow[qi]; s1 += w_ * xr[qi]; s2 += w_ * zr[qi]; }
    p.xf[g] = f2b(s1);
    p.zf[g] = f2b(s2);
  }
  // zero initial h (bf16) and c (f32) for both encoders
  uint4 zz; zz.x = zz.y = zz.z = zz.w = 0u;
  for (int g = gtid; g < 32768; g += NT_ALL) { ((uint4*)p.he0)[g] = zz; ((uint4*)p.hp0)[g] = zz; }
  for (int g = gtid; g < 65536; g += NT_ALL) { ((uint4*)p.c_e)[g] = zz; ((uint4*)p.c_ep)[g] = zz; }
}

// --------------------------- attention (1 row / block) ---------------------
DEV void attention(const Params& p, int b, int tid, char* sm) {
  u16*   catl = (u16*)sm;                 // [21][1024] bf16 = 43008 B
  float* cl   = (float*)(sm + 43008);     // [1024] f32
  float* sc   = (float*)(sm + 47104);     // [21]
  for (int g = tid; g < 2688; g += NTHR) {
    int t = g >> 7, hu = g & 127;
    ((uint4*)catl)[g] = *(const uint4*)(p.cat + ((size_t)(t * 256 + b)) * 1024 + hu * 8);
  }
  for (int g = tid; g < 256; g += NTHR)
    ((uint4*)cl)[g] = ((const uint4*)(p.c_e + (size_t)b * 1024))[g];
  __syncthreads();
  const int wv = tid >> 6, l = tid & 63;
  for (int t = wv; t < 21; t += 8) {
    float s = 0.f;
    const u16* cr = catl + t * 1024;
    for (int hh = l; hh < 1024; hh += 64) s += cl[hh] * b2f(cr[hh]);
#pragma unroll
    for (int o = 32; o; o >>= 1) s += __shfl_down(s, o);
    if (l == 0) sc[t] = s;
  }
  __syncthreads();
  float m = -1e30f;
#pragma unroll
  for (int t = 0; t < 21; ++t) m = fmaxf(m, sc[t]);
  float e[21]; float den = 0.f;
#pragma unroll
  for (int t = 0; t < 21; ++t) { e[t] = __expf(sc[t] - m); den += e[t]; }
  float inv = 1.0f / den;
  const int h0 = tid * 2;
  float a0 = 0.f, a1 = 0.f;
#pragma unroll
  for (int t = 0; t < 21; ++t) {
    float w_ = e[t] * inv;
    a0 += w_ * b2f(catl[t * 1024 + h0]);
    a1 += w_ * b2f(catl[t * 1024 + h0 + 1]);
  }
  ((unsigned*)(p.atth + (size_t)b * 1024))[tid] = pk2(a0, a1);
}

// ------------------------- final projection (1 b / block) ------------------
DEV void finalproj(const Params& p, int b, int tid, char* sm) {
  u16* hl = (u16*)sm;                     // [25][1024] bf16 = 51200 B
  for (int g = tid; g < 3200; g += NTHR) {
    int t = g >> 7, hu = g & 127;
    ((uint4*)hl)[g] = *(const uint4*)(p.hs + ((size_t)(t * 256 + b)) * 1024 + hu * 8);
  }
  __syncthreads();
  if (tid < 330) {
    int pcol = tid % 66, tg = tid / 66;   // 5 groups of 5 timesteps
    float acc[5] = {0.f, 0.f, 0.f, 0.f, 0.f};
    const u16* wrow = p.tpw + (size_t)pcol * 1024;
    for (int hc = 0; hc < 128; ++hc) {
      uint4 wv4 = ((const uint4*)wrow)[hc];
      float wf[8];
      wf[0] = b2f(wv4.x & 0xffff); wf[1] = b2f(wv4.x >> 16);
      wf[2] = b2f(wv4.y & 0xffff); wf[3] = b2f(wv4.y >> 16);
      wf[4] = b2f(wv4.z & 0xffff); wf[5] = b2f(wv4.z >> 16);
      wf[6] = b2f(wv4.w & 0xffff); wf[7] = b2f(wv4.w >> 16);
#pragma unroll
      for (int r = 0; r < 5; ++r) {
        int t = tg * 5 + r;
        uint4 hv = ((const uint4*)(hl + t * 1024))[hc];
        float s;
        s  = wf[0] * b2f(hv.x & 0xffff) + wf[1] * b2f(hv.x >> 16);
        s += wf[2] * b2f(hv.y & 0xffff) + wf[3] * b2f(hv.y >> 16);
        s += wf[4] * b2f(hv.z & 0xffff) + wf[5] * b2f(hv.z >> 16);
        s += wf[6] * b2f(hv.w & 0xffff) + wf[7] * b2f(hv.w >> 16);
        acc[r] += s;
      }
    }
    float bb = p.tp_b[pcol];
#pragma unroll
    for (int r = 0; r < 5; ++r) {
      int t = tg * 5 + r;
      size_t o = (size_t)b * 1650 + (size_t)t * 66 + pcol;
      p.out[o] = acc[r] + bb + p.resid[o];
    }
  }
}

// ------------------------------- main kernel -------------------------------
__global__ __launch_bounds__(NTHR) void model_kernel(Params p) {
  cg::grid_group gg = cg::this_grid();
  __shared__ __align__(16) char sm[53248];
  const int tid = threadIdx.x;
  const int bid = blockIdx.x;
  const int gtid = bid * NTHR + tid;

  phase0a(p, gtid);
  gg.sync();

  // P0b: Wdec[:,0:1024] = (gate-permuted dec_wih) @ lin_w  (lin layer fused)
#pragma unroll 1
  for (int i = 0; i < 4; ++i) {
    int tt = bid * 4 + i;
    int m0w = (tt & 63) << 6;
    int n0w = (tt >> 6) << 6;
    f32x4_t acc[2]; acc[0] = fzero4(); acc[1] = fzero4();
    gemm64(p.wihP, 512, 512, (const u16*)0, 0, p.linT, 512, 512, m0w, n0w, tid, sm, acc);
    wx_store(acc, tid, p.Wdec, m0w, n0w);
  }
  gg.sync();

  // XCD-grouped tile mapping: same n-tiles stay on one XCD's L2 across steps
  const int xcd = bid & 7, qq = bid >> 3;
  const int m0 = (qq & 3) << 6;
  const int n0 = (xcd * 8 + (qq >> 2)) << 6;

  // P1: both encoders, 10 steps (each block: one enc tile + one encp tile)
#pragma unroll 1
  for (int t = 0; t < 10; ++t) {
    const u16* hre = (t & 1) ? p.he1 : p.he0;
    u16*       hwe = (t & 1) ? p.he0 : p.he1;
    const u16* hrp = (t & 1) ? p.hp1 : p.hp0;
    u16*       hwp = (t & 1) ? p.hp0 : p.hp1;
    f32x4_t acc[2]; acc[0] = fzero4(); acc[1] = fzero4();
    gemm64(p.xf + (size_t)t * 131072, 512, 512, hre, 1024, p.Wenc, 1536, 1536, m0, n0, tid, sm, acc);
    lstm_ep(acc, tid, sm, p.bias_e, p.c_e, hwe, p.cat + (size_t)t * 262144, (u16*)0, m0, n0);
    acc[0] = fzero4(); acc[1] = fzero4();
    gemm64(p.zf + (size_t)t * 131072, 512, 512, hrp, 1024, p.Wencp, 1536, 1536, m0, n0, tid, sm, acc);
    lstm_ep(acc, tid, sm, p.bias_ep, p.c_ep, hwp, p.cat + (size_t)(11 + t) * 262144, (u16*)0, m0, n0);
    gg.sync();
  }

  // P2: decoder init h0 = h_n (enc final, lands in he0); cat slot 10 = h_n
  if (gtid < 32768) {
    uint4 v = ((const uint4*)p.he0)[gtid];
    ((uint4*)p.hd0)[gtid] = v;
    ((uint4*)(p.cat + (size_t)10 * 262144))[gtid] = v;
  }
  gg.sync();

  // P3: decoder, 25 steps: attention phase then gates GEMM (K=2048) + update
#pragma unroll 1
  for (int s = 0; s < 25; ++s) {
    attention(p, bid, tid, sm);
    gg.sync();
    const u16* hrd = (s & 1) ? p.hd1 : p.hd0;
    u16*       hwd = (s & 1) ? p.hd0 : p.hd1;
    f32x4_t acc[2]; acc[0] = fzero4(); acc[1] = fzero4();
    gemm64(hrd, 1024, 1024, p.atth, 1024, p.Wdec, 2048, 2048, m0, n0, tid, sm, acc);
    lstm_ep(acc, tid, sm, p.bias_d, p.c_e, hwd, p.cat + (size_t)10 * 262144,
            p.hs + (size_t)s * 262144, m0, n0);
    gg.sync();
  }

  // P4: out = dec_h @ tp_w.T + tp_b + for_resid
  finalproj(p, bid, tid, sm);
}

// ------------------------------- host launch -------------------------------
extern "C" void kernel_launch(void* const* d_in, const int* in_sizes, int n_in,
                              void* d_out, int out_size, void* d_ws, size_t ws_size,
                              hipStream_t stream) {
  (void)in_sizes; (void)n_in; (void)out_size;
  Params P;
  P.x     = (const float*)d_in[0];
  P.z     = (const float*)d_in[1];
  P.resid = (const float*)d_in[2];
  P.tf_w  = (const float*)d_in[3];
  P.tf_b  = (const float*)d_in[4];
  P.e_wih = (const float*)d_in[5];
  P.e_whh = (const float*)d_in[6];
  P.e_bih = (const float*)d_in[7];
  P.e_bhh = (const float*)d_in[8];
  P.p_wih = (const float*)d_in[9];
  P.p_whh = (const float*)d_in[10];
  P.p_bih = (const float*)d_in[11];
  P.p_bhh = (const float*)d_in[12];
  P.d_wih = (const float*)d_in[13];
  P.d_whh = (const float*)d_in[14];
  P.d_bih = (const float*)d_in[15];
  P.d_bhh = (const float*)d_in[16];
  P.lin_w = (const float*)d_in[17];
  P.lin_b = (const float*)d_in[18];
  P.tp_w  = (const float*)d_in[19];
  P.tp_b  = (const float*)d_in[20];

  char* w = (char*)d_ws;
  size_t o = 0;
  auto take = [&](size_t bytes) { char* r = w + o; o = (o + bytes + 255) & ~(size_t)255; return r; };
  P.Wenc  = (u16*)take(4096ull * 1536 * 2);
  P.Wencp = (u16*)take(4096ull * 1536 * 2);
  P.Wdec  = (u16*)take(4096ull * 2048 * 2);
  P.wihP  = (u16*)take(4096ull * 512 * 2);
  P.linT  = (u16*)take(1024ull * 512 * 2);
  P.tpw   = (u16*)take(66ull * 1024 * 2);
  P.bias_e  = (float*)take(4096 * 4);
  P.bias_ep = (float*)take(4096 * 4);
  P.bias_d  = (float*)take(4096 * 4);
  P.xf  = (u16*)take(10ull * 256 * 512 * 2);
  P.zf  = (u16*)take(10ull * 256 * 512 * 2);
  P.he0 = (u16*)take(256ull * 1024 * 2);
  P.he1 = (u16*)take(256ull * 1024 * 2);
  P.hp0 = (u16*)take(256ull * 1024 * 2);
  P.hp1 = (u16*)take(256ull * 1024 * 2);
  P.hd0 = (u16*)take(256ull * 1024 * 2);
  P.hd1 = (u16*)take(256ull * 1024 * 2);
  P.c_e  = (float*)take(256ull * 1024 * 4);
  P.c_ep = (float*)take(256ull * 1024 * 4);
  P.atth = (u16*)take(256ull * 1024 * 2);
  P.cat  = (u16*)take(21ull * 256 * 1024 * 2);
  P.hs   = (u16*)take(25ull * 256 * 1024 * 2);
  P.out  = (float*)d_out;

  if (o > ws_size) return;  // workspace too small: fail cleanly, no corruption

  void* args[] = { &P };
  hipLaunchCooperativeKernel((const void*)model_kernel, dim3(NBLK, 1, 1),
                             dim3(NTHR, 1, 1), args, 0, stream);
}

// Round 2
// 935.710 us; speedup vs baseline: 3.0164x; 3.0164x over previous
//
#include <hip/hip_runtime.h>
#include <hip/hip_bf16.h>
#include <hip/hip_cooperative_groups.h>

namespace cg = cooperative_groups;

#define DEV __device__ __forceinline__

typedef unsigned short u16;
typedef short bf16x8_t __attribute__((ext_vector_type(8)));
typedef float f32x4_t __attribute__((ext_vector_type(4)));

// Model dims: B=256 H=1024 F=512 P=66 T_IN=10 T_OUT=25, gates 4H=4096
// enc K = F+H = 1536 ; dec K (lin fused) = H+H = 2048
constexpr int NBLK = 256;
constexpr int NTHR = 512;
constexpr int NT_ALL = NBLK * NTHR; // 131072
constexpr size_t HSTRIDE = 256 * 1024; // elements per h buffer [b][1024]

struct Params {
  const float *x, *z, *resid, *tf_w, *tf_b;
  const float *e_wih, *e_whh, *e_bih, *e_bhh;
  const float *p_wih, *p_whh, *p_bih, *p_bhh;
  const float *d_wih, *d_whh, *d_bih, *d_bhh;
  const float *lin_w, *lin_b, *tp_w, *tp_b;
  u16 *Wenc, *Wencp, *Wdec, *wihP, *linT, *tpw;
  float *bias_e, *bias_ep, *bias_d, *bias_part;
  u16 *xf, *zf;
  u16 *he, *hp;        // 11 step-buffers each: he + t*HSTRIDE
  u16 *hs;             // 25 decoder h buffers (also the finalproj input)
  u16 *atth;           // 25 step-buffers
  float *c_pub;        // 2 ping-pong f32 [256][1024]
  unsigned *bar;       // 8 counters, 64B apart
  float *out;
};

DEV float b2f(u16 v) { unsigned u = ((unsigned)v) << 16; float f; __builtin_memcpy(&f, &u, 4); return f; }
DEV u16 f2b(float f) {
  unsigned u; __builtin_memcpy(&u, &f, 4);
  unsigned r = u + 0x7fffu + ((u >> 16) & 1u);   // RNE
  return (u16)(r >> 16);
}
DEV unsigned pk2(float a, float b) { return (unsigned)f2b(a) | ((unsigned)f2b(b) << 16); }
DEV uint4 cvt8(const float* s) {
  float4 a = *(const float4*)s;
  float4 b = *(const float4*)(s + 4);
  uint4 r;
  r.x = pk2(a.x, a.y); r.y = pk2(a.z, a.w);
  r.z = pk2(b.x, b.y); r.w = pk2(b.z, b.w);
  return r;
}
DEV float sigm(float x) { return 1.0f / (1.0f + __expf(-x)); }
DEV f32x4_t fzero4() { f32x4_t v = {0.f, 0.f, 0.f, 0.f}; return v; }

DEV void gll16(const void* g, void* l) {
  __builtin_amdgcn_global_load_lds(
      (const __attribute__((address_space(1))) void*)g,
      (__attribute__((address_space(3))) void*)l, 16, 0, 0);
}

// sc1 write-through store / bypass load helpers (agent scope, relaxed)
template <typename T> DEV void st_wt(T* p, T v) {
  __hip_atomic_store(p, v, __ATOMIC_RELAXED, __HIP_MEMORY_SCOPE_AGENT);
}
template <typename T> DEV T ld_byp(const T* p) {
  return __hip_atomic_load(p, __ATOMIC_RELAXED, __HIP_MEMORY_SCOPE_AGENT);
}

// ---- fence-free grid barrier: 8 split monotonic counters, no L2 flush ----
DEV void gridbar(unsigned* ctrs, unsigned ep32, int tid, int bid) {
  asm volatile("s_waitcnt vmcnt(0)" ::: "memory");   // own sc1 stores complete
  __syncthreads();
  if (tid == 0) atomicAdd(&ctrs[(bid & 7) * 16], 1u);  // device-scope RMW
  if (tid < 8) {
    const unsigned tgt = ep32 * 32u;                 // 32 blocks per counter
    while (ld_byp(&ctrs[tid * 16]) < tgt) __builtin_amdgcn_s_sleep(2);
  }
  __syncthreads();
}

// ---------------- 64x64-tile bf16 GEMM, K multiple of 64 -------------------
// Depth-2 prefetch, 4 LDS buffers, raw s_barrier + counted vmcnt (no drain).
// A rows from xa (k < xcols, stride ldx) then ha (stride ldh); B rows = W[n][k].
// Source-side XOR swizzle (16B unit ^= row&7) + same XOR on ds_read_b128.
DEV void gemm64(const u16* __restrict__ xa, int ldx, int xcols,
                const u16* __restrict__ ha, int ldh,
                const u16* __restrict__ wsrc, int ldw, int K,
                int m0, int n0, int tid, char* sm, f32x4_t acc[2]) {
  char* lA = sm;             // 4 bufs x 8KB
  char* lB = sm + 32768;     // 4 bufs x 8KB
  const int NK = K >> 6;
  const int row = tid >> 3, uu = tid & 7;
  const int usw = uu ^ (row & 7);
  const int wv = tid >> 6;
  char* la_base = lA + (wv << 10);
  char* lb_base = lB + (wv << 10);

  auto stage = [&](int ks) {
    const int k0 = ks << 6;
    const u16* ga;
    if (k0 < xcols) ga = xa + (size_t)(m0 + row) * ldx + (k0 + usw * 8);
    else            ga = ha + (size_t)(m0 + row) * ldh + (k0 - xcols + usw * 8);
    const u16* gb = wsrc + (size_t)(n0 + row) * ldw + (k0 + usw * 8);
    const int sel = (ks & 3) << 13;
    gll16(ga, la_base + sel);
    gll16(gb, lb_base + sel);
  };

  const int l = tid & 63, l15 = l & 15, lhi = l >> 4;
  const int wr = wv >> 1, wc = wv & 1;       // 4x2 wave grid, wave tile 16x32
  const int rA = wr * 16 + l15;
  const int aoff0 = rA * 128 + ((lhi ^ (rA & 7)) << 4);
  const int aoff1 = rA * 128 + (((lhi + 4) ^ (rA & 7)) << 4);
  const int nB0 = wc * 32 + l15, nB1 = nB0 + 16;
  const int boff00 = nB0 * 128 + ((lhi ^ (nB0 & 7)) << 4);
  const int boff01 = nB0 * 128 + (((lhi + 4) ^ (nB0 & 7)) << 4);
  const int boff10 = nB1 * 128 + ((lhi ^ (nB1 & 7)) << 4);
  const int boff11 = nB1 * 128 + (((lhi + 4) ^ (nB1 & 7)) << 4);

  stage(0);
  stage(1);
#pragma unroll 1
  for (int ks = 0; ks < NK; ++ks) {
    if (ks + 2 < NK) {
      stage(ks + 2);
      asm volatile("s_waitcnt vmcnt(4)" ::: "memory");   // stage(ks) landed
    } else if (ks + 1 < NK) {
      asm volatile("s_waitcnt vmcnt(2)" ::: "memory");
    } else {
      asm volatile("s_waitcnt vmcnt(0)" ::: "memory");
    }
    __builtin_amdgcn_s_barrier();
    const char* A  = lA + ((ks & 3) << 13);
    const char* Bb = lB + ((ks & 3) << 13);
    bf16x8_t a0  = *(const bf16x8_t*)(A + aoff0);
    bf16x8_t a1  = *(const bf16x8_t*)(A + aoff1);
    bf16x8_t b00 = *(const bf16x8_t*)(Bb + boff00);
    bf16x8_t b01 = *(const bf16x8_t*)(Bb + boff01);
    bf16x8_t b10 = *(const bf16x8_t*)(Bb + boff10);
    bf16x8_t b11 = *(const bf16x8_t*)(Bb + boff11);
    acc[0] = __builtin_amdgcn_mfma_f32_16x16x32_bf16(a0, b00, acc[0], 0, 0, 0);
    acc[0] = __builtin_amdgcn_mfma_f32_16x16x32_bf16(a1, b01, acc[0], 0, 0, 0);
    acc[1] = __builtin_amdgcn_mfma_f32_16x16x32_bf16(a0, b10, acc[1], 0, 0, 0);
    acc[1] = __builtin_amdgcn_mfma_f32_16x16x32_bf16(a1, b11, acc[1], 0, 0, 0);
  }
  asm volatile("s_waitcnt vmcnt(0)" ::: "memory");
  __builtin_amdgcn_s_barrier();               // LDS free for reuse
}

// ----------------- LSTM pointwise epilogue, c in registers -----------------
DEV void lstm_ep_reg(const f32x4_t acc[2], int tid, char* sm,
                     const float* __restrict__ bias, float cc[2],
                     u16* __restrict__ hw, float* __restrict__ cpub,
                     int m0, int n0) {
  float* gl = (float*)sm;               // [64][68] f32 overlay
  const int l = tid & 63, l15 = l & 15, lhi = l >> 4;
  const int wv = tid >> 6, wr = wv >> 1, wc = wv & 1;
#pragma unroll
  for (int j = 0; j < 2; ++j)
#pragma unroll
    for (int qq = 0; qq < 4; ++qq)
      gl[(wr * 16 + lhi * 4 + qq) * 68 + wc * 32 + j * 16 + l15] = acc[j][qq];
  __syncthreads();
#pragma unroll
  for (int it = 0; it < 2; ++it) {
    int idx = it * 512 + tid;           // 1024 items: 64 rows x 16 j
    int r = idx >> 4, jj = idx & 15;
    f32x4_t g4 = *(const f32x4_t*)(gl + r * 68 + jj * 4);
    f32x4_t b4 = *(const f32x4_t*)(bias + n0 + jj * 4);
    float ig = sigm(g4[0] + b4[0]);
    float fg = sigm(g4[1] + b4[1]);
    float g_ = tanhf(g4[2] + b4[2]);
    float og = sigm(g4[3] + b4[3]);
    float cn = fg * cc[it] + ig * g_;
    cc[it] = cn;
    float hn = og * tanhf(cn);
    size_t off = (size_t)(m0 + r) * 1024 + (n0 >> 2) + jj;
    st_wt(&hw[off], f2b(hn));
    if (cpub) st_wt(&cpub[off], cn);
  }
  __syncthreads();
}

DEV void wx_store(const f32x4_t acc[2], int tid, u16* __restrict__ Wdec,
                  int m0, int n0) {
  const int l = tid & 63, l15 = l & 15, lhi = l >> 4;
  const int wv = tid >> 6, wr = wv >> 1, wc = wv & 1;
#pragma unroll
  for (int j = 0; j < 2; ++j)
#pragma unroll
    for (int qq = 0; qq < 4; ++qq) {
      int r = m0 + wr * 16 + lhi * 4 + qq;
      int c = n0 + wc * 32 + j * 16 + l15;
      st_wt(&Wdec[(size_t)r * 2048 + c], f2b(acc[j][qq]));
    }
}

// --------------------------- phase 0a: conversions -------------------------
DEV void phase0a(const Params& p, int gtid) {
  for (int g = gtid; g < 786432; g += NT_ALL) {     // enc/encp 4096 x 192 units
    int row = g / 192;
    int u = g - row * 192;
    int k = u * 8;
    int nsrc = (row & 3) * 1024 + (row >> 2);       // gate-interleaved rows
    const float* s1 = (k < 512) ? (p.e_wih + (size_t)nsrc * 512 + k)
                                : (p.e_whh + (size_t)nsrc * 1024 + (k - 512));
    ((uint4*)p.Wenc)[g] = cvt8(s1);
    const float* s2 = (k < 512) ? (p.p_wih + (size_t)nsrc * 512 + k)
                                : (p.p_whh + (size_t)nsrc * 1024 + (k - 512));
    ((uint4*)p.Wencp)[g] = cvt8(s2);
  }
  for (int g = gtid; g < 524288; g += NT_ALL) {     // dec whh -> Wdec[:,1024:]
    int row = g >> 7, u = g & 127;
    int nsrc = (row & 3) * 1024 + (row >> 2);
    ((uint4*)p.Wdec)[row * 256 + 128 + u] = cvt8(p.d_whh + (size_t)nsrc * 1024 + u * 8);
  }
  for (int g = gtid; g < 262144; g += NT_ALL) {     // dec wih (gate-permuted)
    int row = g >> 6, u = g & 63;
    int nsrc = (row & 3) * 1024 + (row >> 2);
    ((uint4*)p.wihP)[g] = cvt8(p.d_wih + (size_t)nsrc * 512 + u * 8);
  }
  for (int g = gtid; g < 524288; g += NT_ALL) {     // lin_w transpose
    int f = g >> 10, h = g & 1023;
    p.linT[(size_t)h * 512 + f] = f2b(p.lin_w[g]);
  }
  for (int g = gtid; g < 8448; g += NT_ALL)
    ((uint4*)p.tpw)[g] = cvt8(p.tp_w + g * 8);
  for (int g = gtid; g < 4096; g += NT_ALL) {       // enc biases
    int nsrc = (g & 3) * 1024 + (g >> 2);
    p.bias_e[g]  = p.e_bih[nsrc] + p.e_bhh[nsrc];
    p.bias_ep[g] = p.p_bih[nsrc] + p.p_bhh[nsrc];
  }
  for (int g = gtid; g < 32768; g += NT_ALL) {      // bias_d partials (wih@lin_b)
    int cell = g >> 3, sub = g & 7;
    int nsrc = (cell & 3) * 1024 + (cell >> 2);
    const float* wr_ = p.d_wih + (size_t)nsrc * 512 + sub * 64;
    const float* lb = p.lin_b + sub * 64;
    float s = 0.f;
    for (int f = 0; f < 64; ++f) s += wr_[f] * lb[f];
    p.bias_part[g] = s;
  }
  for (int g = gtid; g < 1310720; g += NT_ALL) {    // ToFeature x,z -> xf,zf
    int n = g & 511, bt = g >> 9;
    int b = bt & 255, t = bt >> 8;
    const float* xr = p.x + ((size_t)b * 10 + t) * 66;
    const float* zr = p.z + ((size_t)b * 10 + t) * 66;
    const float* wrow = p.tf_w + (size_t)n * 66;
    float s1 = p.tf_b[n], s2 = s1;
    for (int qi = 0; qi < 66; ++qi) { float w_ = wrow[qi]; s1 += w_ * xr[qi]; s2 += w_ * zr[qi]; }
    p.xf[g] = f2b(s1);
    p.zf[g] = f2b(s2);
  }
  uint4 zz; zz.x = zz.y = zz.z = zz.w = 0u;         // zero h0 for both encoders
  for (int g = gtid; g < 32768; g += NT_ALL) { ((uint4*)p.he)[g] = zz; ((uint4*)p.hp)[g] = zz; }
}

// --------------------------- attention (1 row / block) ---------------------
DEV void attention(const Params& p, const u16* hd_prev, const float* cpub,
                   u16* atth_s, int b, int tid, char* sm) {
  u16*   catl = (u16*)sm;                 // [21][1024] bf16 = 43008 B
  float* cl   = (float*)(sm + 43008);     // [1024] f32
  float* sc   = (float*)(sm + 47104);     // [21]
  for (int g = tid; g < 2688; g += NTHR) {
    int t = g >> 7, hu = g & 127;
    const u16* src;
    if (t < 10)       src = p.he + (size_t)(t + 1) * HSTRIDE;
    else if (t == 10) src = hd_prev;
    else              src = p.hp + (size_t)(t - 10) * HSTRIDE;
    ((uint4*)catl)[g] = *(const uint4*)(src + (size_t)b * 1024 + hu * 8);
  }
  for (int g = tid; g < 512; g += NTHR) {  // c via sc1 (ping-pong buffer reuse)
    unsigned long long v = ld_byp(((const unsigned long long*)(cpub + (size_t)b * 1024)) + g);
    ((unsigned long long*)cl)[g] = v;
  }
  __syncthreads();
  const int wv = tid >> 6, l = tid & 63;
  for (int t = wv; t < 21; t += 8) {
    float s = 0.f;
    const u16* cr = catl + t * 1024;
    for (int hh = l; hh < 1024; hh += 64) s += cl[hh] * b2f(cr[hh]);
#pragma unroll
    for (int o = 32; o; o >>= 1) s += __shfl_down(s, o);
    if (l == 0) sc[t] = s;
  }
  __syncthreads();
  float m = -1e30f;
#pragma unroll
  for (int t = 0; t < 21; ++t) m = fmaxf(m, sc[t]);
  float e[21]; float den = 0.f;
#pragma unroll
  for (int t = 0; t < 21; ++t) { e[t] = __expf(sc[t] - m); den += e[t]; }
  float inv = 1.0f / den;
  const int h0 = tid * 2;
  float a0 = 0.f, a1 = 0.f;
#pragma unroll
  for (int t = 0; t < 21; ++t) {
    float w_ = e[t] * inv;
    a0 += w_ * b2f(catl[t * 1024 + h0]);
    a1 += w_ * b2f(catl[t * 1024 + h0 + 1]);
  }
  st_wt(((unsigned*)(atth_s + (size_t)b * 1024)) + tid, pk2(a0, a1));
}

// ------------------------- final projection (1 b / block) ------------------
DEV void finalproj(const Params& p, int b, int tid, char* sm) {
  u16* hl = (u16*)sm;                     // [25][1024] bf16 = 51200 B
  for (int g = tid; g < 3200; g += NTHR) {
    int t = g >> 7, hu = g & 127;
    ((uint4*)hl)[g] = *(const uint4*)(p.hs + ((size_t)(t * 256 + b)) * 1024 + hu * 8);
  }
  __syncthreads();
  if (tid < 330) {
    int pcol = tid % 66, tg = tid / 66;   // 5 groups of 5 timesteps
    float acc[5] = {0.f, 0.f, 0.f, 0.f, 0.f};
    const u16* wrow = p.tpw + (size_t)pcol * 1024;
    for (int hc = 0; hc < 128; ++hc) {
      uint4 wv4 = ((const uint4*)wrow)[hc];
      float wf[8];
      wf[0] = b2f(wv4.x & 0xffff); wf[1] = b2f(wv4.x >> 16);
      wf[2] = b2f(wv4.y & 0xffff); wf[3] = b2f(wv4.y >> 16);
      wf[4] = b2f(wv4.z & 0xffff); wf[5] = b2f(wv4.z >> 16);
      wf[6] = b2f(wv4.w & 0xffff); wf[7] = b2f(wv4.w >> 16);
#pragma unroll
      for (int r = 0; r < 5; ++r) {
        int t = tg * 5 + r;
        uint4 hv = ((const uint4*)(hl + t * 1024))[hc];
        float s;
        s  = wf[0] * b2f(hv.x & 0xffff) + wf[1] * b2f(hv.x >> 16);
        s += wf[2] * b2f(hv.y & 0xffff) + wf[3] * b2f(hv.y >> 16);
        s += wf[4] * b2f(hv.z & 0xffff) + wf[5] * b2f(hv.z >> 16);
        s += wf[6] * b2f(hv.w & 0xffff) + wf[7] * b2f(hv.w >> 16);
        acc[r] += s;
      }
    }
    float bb = p.tp_b[pcol];
#pragma unroll
    for (int r = 0; r < 5; ++r) {
      int t = tg * 5 + r;
      size_t o = (size_t)b * 1650 + (size_t)t * 66 + pcol;
      p.out[o] = acc[r] + bb + p.resid[o];
    }
  }
}

// ------------------------------- main kernel -------------------------------
__global__ __launch_bounds__(NTHR) void model_kernel(Params p) {
  cg::grid_group gg = cg::this_grid();
  __shared__ __align__(16) char sm[65536];
  const int tid = threadIdx.x;
  const int bid = blockIdx.x;
  const int gtid = bid * NTHR + tid;

  phase0a(p, gtid);
  if (bid == 0 && tid < 8) st_wt(&p.bar[tid * 16], 0u);   // barrier reset
  gg.sync();                      // ONLY full-fence sync (flushes phase0 writes)
  unsigned bep = 0;

  // P0b: finalize bias_d; Wdec[:,0:1024] = (gate-permuted dec_wih) @ lin_w
  for (int g = gtid; g < 4096; g += NT_ALL) {
    int nsrc = (g & 3) * 1024 + (g >> 2);
    float s = p.d_bih[nsrc] + p.d_bhh[nsrc];
#pragma unroll
    for (int k8 = 0; k8 < 8; ++k8) s += p.bias_part[g * 8 + k8];
    st_wt(&p.bias_d[g], s);
  }
#pragma unroll 1
  for (int i = 0; i < 4; ++i) {
    int tt = bid * 4 + i;
    int m0w = (tt & 63) << 6;
    int n0w = (tt >> 6) << 6;
    f32x4_t acc[2]; acc[0] = fzero4(); acc[1] = fzero4();
    gemm64(p.wihP, 512, 512, (const u16*)0, 0, p.linT, 512, 512, m0w, n0w, tid, sm, acc);
    wx_store(acc, tid, p.Wdec, m0w, n0w);
  }
  ++bep; gridbar(p.bar, bep, tid, bid);

  // XCD-grouped tile mapping: same n-tiles stay on one XCD's L2 across steps
  const int xcd = bid & 7, qq = bid >> 3;
  const int m0 = (qq & 3) << 6;
  const int n0 = (xcd * 8 + (qq >> 2)) << 6;

  float ce[2] = {0.f, 0.f}, cp[2] = {0.f, 0.f};   // c in registers, all steps

  // P1: both encoders, 10 steps
#pragma unroll 1
  for (int t = 0; t < 10; ++t) {
    f32x4_t acc[2]; acc[0] = fzero4(); acc[1] = fzero4();
    gemm64(p.xf + (size_t)t * 131072, 512, 512, p.he + (size_t)t * HSTRIDE, 1024,
           p.Wenc, 1536, 1536, m0, n0, tid, sm, acc);
    lstm_ep_reg(acc, tid, sm, p.bias_e, ce, p.he + (size_t)(t + 1) * HSTRIDE,
                (t == 9) ? p.c_pub : (float*)0, m0, n0);
    acc[0] = fzero4(); acc[1] = fzero4();
    gemm64(p.zf + (size_t)t * 131072, 512, 512, p.hp + (size_t)t * HSTRIDE, 1024,
           p.Wencp, 1536, 1536, m0, n0, tid, sm, acc);
    lstm_ep_reg(acc, tid, sm, p.bias_ep, cp, p.hp + (size_t)(t + 1) * HSTRIDE,
                (float*)0, m0, n0);
    ++bep; gridbar(p.bar, bep, tid, bid);
  }

  // P3: decoder, 25 steps. c continues in ce[]; h_dec[0] aliases he[10].
#pragma unroll 1
  for (int s = 0; s < 25; ++s) {
    const u16* hd_prev = (s == 0) ? (p.he + (size_t)10 * HSTRIDE)
                                  : (p.hs + (size_t)(s - 1) * HSTRIDE);
    u16* atth_s = p.atth + (size_t)s * HSTRIDE;
    attention(p, hd_prev, p.c_pub + (size_t)(s & 1) * 262144, atth_s, bid, tid, sm);
    ++bep; gridbar(p.bar, bep, tid, bid);
    f32x4_t acc[2]; acc[0] = fzero4(); acc[1] = fzero4();
    gemm64(hd_prev, 1024, 1024, atth_s, 1024, p.Wdec, 2048, 2048, m0, n0, tid, sm, acc);
    lstm_ep_reg(acc, tid, sm, p.bias_d, ce, p.hs + (size_t)s * HSTRIDE,
                p.c_pub + (size_t)((s + 1) & 1) * 262144, m0, n0);
    ++bep; gridbar(p.bar, bep, tid, bid);
  }

  // P4: out = dec_h @ tp_w.T + tp_b + for_resid
  finalproj(p, bid, tid, sm);
}

// ------------------------------- host launch -------------------------------
extern "C" void kernel_launch(void* const* d_in, const int* in_sizes, int n_in,
                              void* d_out, int out_size, void* d_ws, size_t ws_size,
                              hipStream_t stream) {
  (void)in_sizes; (void)n_in; (void)out_size;
  Params P;
  P.x     = (const float*)d_in[0];
  P.z     = (const float*)d_in[1];
  P.resid = (const float*)d_in[2];
  P.tf_w  = (const float*)d_in[3];
  P.tf_b  = (const float*)d_in[4];
  P.e_wih = (const float*)d_in[5];
  P.e_whh = (const float*)d_in[6];
  P.e_bih = (const float*)d_in[7];
  P.e_bhh = (const float*)d_in[8];
  P.p_wih = (const float*)d_in[9];
  P.p_whh = (const float*)d_in[10];
  P.p_bih = (const float*)d_in[11];
  P.p_bhh = (const float*)d_in[12];
  P.d_wih = (const float*)d_in[13];
  P.d_whh = (const float*)d_in[14];
  P.d_bih = (const float*)d_in[15];
  P.d_bhh = (const float*)d_in[16];
  P.lin_w = (const float*)d_in[17];
  P.lin_b = (const float*)d_in[18];
  P.tp_w  = (const float*)d_in[19];
  P.tp_b  = (const float*)d_in[20];

  char* w = (char*)d_ws;
  size_t o = 0;
  auto take = [&](size_t bytes) { char* r = w + o; o = (o + bytes + 255) & ~(size_t)255; return r; };
  P.Wenc  = (u16*)take(4096ull * 1536 * 2);
  P.Wencp = (u16*)take(4096ull * 1536 * 2);
  P.Wdec  = (u16*)take(4096ull * 2048 * 2);
  P.wihP  = (u16*)take(4096ull * 512 * 2);
  P.linT  = (u16*)take(1024ull * 512 * 2);
  P.tpw   = (u16*)take(66ull * 1024 * 2);
  P.bias_e    = (float*)take(4096 * 4);
  P.bias_ep   = (float*)take(4096 * 4);
  P.bias_d    = (float*)take(4096 * 4);
  P.bias_part = (float*)take(32768 * 4);
  P.xf  = (u16*)take(10ull * 256 * 512 * 2);
  P.zf  = (u16*)take(10ull * 256 * 512 * 2);
  P.he  = (u16*)take(11ull * 256 * 1024 * 2);
  P.hp  = (u16*)take(11ull * 256 * 1024 * 2);
  P.hs  = (u16*)take(25ull * 256 * 1024 * 2);
  P.atth = (u16*)take(25ull * 256 * 1024 * 2);
  P.c_pub = (float*)take(2ull * 256 * 1024 * 4);
  P.bar = (unsigned*)take(8 * 64);
  P.out = (float*)d_out;

  if (o > ws_size) return;  // workspace too small: fail cleanly, no corruption

  void* args[] = { &P };
  hipLaunchCooperativeKernel((const void*)model_kernel, dim3(NBLK, 1, 1),
                             dim3(NTHR, 1, 1), args, 0, stream);
}

// Round 3
// 815.072 us; speedup vs baseline: 3.4629x; 1.1480x over previous
//
#include <hip/hip_runtime.h>
#include <hip/hip_bf16.h>
#include <hip/hip_cooperative_groups.h>

namespace cg = cooperative_groups;

#define DEV __device__ __forceinline__

typedef unsigned short u16;
typedef short bf16x8_t __attribute__((ext_vector_type(8)));
typedef float f32x4_t __attribute__((ext_vector_type(4)));

// Model dims: B=256 H=1024 F=512 P=66 T_IN=10 T_OUT=25, gates 4H=4096
// enc K = F+H = 1536 ; dec K split: 1024 (h part) + 1024 (atth part, lin fused)
constexpr int NBLK = 256;
constexpr int NTHR = 512;
constexpr int NT_ALL = NBLK * NTHR; // 131072
constexpr size_t HSTRIDE = 256 * 1024; // elements per h buffer [b][1024]

struct Params {
  const float *x, *z, *resid, *tf_w, *tf_b;
  const float *e_wih, *e_whh, *e_bih, *e_bhh;
  const float *p_wih, *p_whh, *p_bih, *p_bhh;
  const float *d_wih, *d_whh, *d_bih, *d_bhh;
  const float *lin_w, *lin_b, *tp_w, *tp_b;
  u16 *Wenc, *Wencp, *Wdec, *wihP, *linT, *tpw;
  float *bias_e, *bias_ep, *bias_d, *bias_part;
  u16 *xf, *zf;
  u16 *he, *hp;        // 11 step-buffers each: he + t*HSTRIDE
  u16 *hs;             // 25 decoder h buffers (also the finalproj input)
  u16 *atth;           // 25 step-buffers
  float *c_pub;        // 2 ping-pong f32 [256][1024]
  unsigned *bar;       // ctr[i*16]: 0..7 global, 8..15 lane pairs
  float *out;
};

DEV float b2f(u16 v) { unsigned u = ((unsigned)v) << 16; float f; __builtin_memcpy(&f, &u, 4); return f; }
DEV u16 f2b(float f) {
  unsigned u; __builtin_memcpy(&u, &f, 4);
  unsigned r = u + 0x7fffu + ((u >> 16) & 1u);   // RNE
  return (u16)(r >> 16);
}
DEV unsigned pk2(float a, float b) { return (unsigned)f2b(a) | ((unsigned)f2b(b) << 16); }
DEV uint4 cvt8(const float* s) {
  float4 a = *(const float4*)s;
  float4 b = *(const float4*)(s + 4);
  uint4 r;
  r.x = pk2(a.x, a.y); r.y = pk2(a.z, a.w);
  r.z = pk2(b.x, b.y); r.w = pk2(b.z, b.w);
  return r;
}
DEV float sigm(float x) { return 1.0f / (1.0f + __expf(-x)); }
DEV f32x4_t fzero4() { f32x4_t v = {0.f, 0.f, 0.f, 0.f}; return v; }

DEV void gll16(const void* g, void* l) {
  __builtin_amdgcn_global_load_lds(
      (const __attribute__((address_space(1))) void*)g,
      (__attribute__((address_space(3))) void*)l, 16, 0, 0);
}

// sc1 write-through store / bypass load helpers (agent scope, relaxed)
template <typename T> DEV void st_wt(T* p, T v) {
  __hip_atomic_store(p, v, __ATOMIC_RELAXED, __HIP_MEMORY_SCOPE_AGENT);
}
template <typename T> DEV T ld_byp(const T* p) {
  return __hip_atomic_load(p, __ATOMIC_RELAXED, __HIP_MEMORY_SCOPE_AGENT);
}

// ---- fence-free barriers: monotonic counters, no L2 flush ----
DEV void gridbar(unsigned* ctrs, unsigned ep, int tid, int bid) {
  asm volatile("s_waitcnt vmcnt(0)" ::: "memory");
  __syncthreads();
  if (tid == 0) atomicAdd(&ctrs[(bid & 7) * 16], 1u);
  if (tid < 8) {
    const unsigned tgt = ep * 32u;
    while (ld_byp(&ctrs[tid * 16]) < tgt) __builtin_amdgcn_s_sleep(2);
  }
  __syncthreads();
}
DEV void lanebar(unsigned* ctrs, unsigned ep, int lane, int j, int tid) {
  asm volatile("s_waitcnt vmcnt(0)" ::: "memory");
  __syncthreads();
  if (tid == 0) atomicAdd(&ctrs[(8 + lane * 2 + (j & 1)) * 16], 1u);
  if (tid < 2) {
    const unsigned tgt = ep * 32u;
    while (ld_byp(&ctrs[(8 + lane * 2 + tid) * 16]) < tgt) __builtin_amdgcn_s_sleep(1);
  }
  __syncthreads();
}

// ---------------- 64x64-tile bf16 GEMM, K multiple of 64 -------------------
// LDS layout: lB = sm[0..32K) 4 slots x 8K; lA = sm[32K..64K) 4 slots x 8K.
// Depth-3 slot pipeline, raw s_barrier + counted vmcnt (never drains mid-loop).
// Source-side XOR swizzle (16B unit ^= row&7) + same XOR on ds_read_b128.
// PM: 0 = stage slots 0,1 at entry; 1 = caller prestaged A+B slots 0,1;
//     2 = caller prestaged B slots 0,1 (drained since), A staged at entry.
template <int PM>
DEV void gemm64(const u16* __restrict__ xa, int ldx, int xcols,
                const u16* __restrict__ ha, int ldh,
                const u16* __restrict__ wsrc, int ldw, int K,
                int m0, int n0, int tid, char* sm, f32x4_t acc[2]) {
  char* lB = sm;
  char* lA = sm + 32768;
  const int NK = K >> 6;
  const int row = tid >> 3, uu = tid & 7;
  const int usw = uu ^ (row & 7);
  const int wv = tid >> 6;
  char* la_base = lA + (wv << 10);
  char* lb_base = lB + (wv << 10);

  auto stageA = [&](int ks) {
    const int k0 = ks << 6;
    const u16* ga;
    if (k0 < xcols) ga = xa + (size_t)(m0 + row) * ldx + (k0 + usw * 8);
    else            ga = ha + (size_t)(m0 + row) * ldh + (k0 - xcols + usw * 8);
    gll16(ga, la_base + ((ks & 3) << 13));
  };
  auto stageB = [&](int ks) {
    const int k0 = ks << 6;
    const u16* gb = wsrc + (size_t)(n0 + row) * ldw + (k0 + usw * 8);
    gll16(gb, lb_base + ((ks & 3) << 13));
  };

  const int l = tid & 63, l15 = l & 15, lhi = l >> 4;
  const int wr = wv >> 1, wc = wv & 1;       // 4x2 wave grid, wave tile 16x32
  const int rA = wr * 16 + l15;
  const int aoff0 = rA * 128 + ((lhi ^ (rA & 7)) << 4);
  const int aoff1 = rA * 128 + (((lhi + 4) ^ (rA & 7)) << 4);
  const int nB0 = wc * 32 + l15, nB1 = nB0 + 16;
  const int boff00 = nB0 * 128 + ((lhi ^ (nB0 & 7)) << 4);
  const int boff01 = nB0 * 128 + (((lhi + 4) ^ (nB0 & 7)) << 4);
  const int boff10 = nB1 * 128 + ((lhi ^ (nB1 & 7)) << 4);
  const int boff11 = nB1 * 128 + (((lhi + 4) ^ (nB1 & 7)) << 4);

  if (PM == 0) { stageA(0); stageB(0); stageA(1); stageB(1); }
  if (PM == 2) { stageA(0); stageA(1); }

#pragma unroll 1
  for (int ks = 0; ks < NK; ++ks) {
    if (ks + 2 < NK) { stageA(ks + 2); stageB(ks + 2); }
    if (ks == 0)            asm volatile("s_waitcnt vmcnt(3)" ::: "memory");
    else if (ks + 2 < NK)   asm volatile("s_waitcnt vmcnt(4)" ::: "memory");
    else if (ks + 2 == NK)  asm volatile("s_waitcnt vmcnt(2)" ::: "memory");
    else                    asm volatile("s_waitcnt vmcnt(0)" ::: "memory");
    __builtin_amdgcn_s_barrier();
    const char* A  = lA + ((ks & 3) << 13);
    const char* Bb = lB + ((ks & 3) << 13);
    bf16x8_t a0  = *(const bf16x8_t*)(A + aoff0);
    bf16x8_t a1  = *(const bf16x8_t*)(A + aoff1);
    bf16x8_t b00 = *(const bf16x8_t*)(Bb + boff00);
    bf16x8_t b01 = *(const bf16x8_t*)(Bb + boff01);
    bf16x8_t b10 = *(const bf16x8_t*)(Bb + boff10);
    bf16x8_t b11 = *(const bf16x8_t*)(Bb + boff11);
    acc[0] = __builtin_amdgcn_mfma_f32_16x16x32_bf16(a0, b00, acc[0], 0, 0, 0);
    acc[0] = __builtin_amdgcn_mfma_f32_16x16x32_bf16(a1, b01, acc[0], 0, 0, 0);
    acc[1] = __builtin_amdgcn_mfma_f32_16x16x32_bf16(a0, b10, acc[1], 0, 0, 0);
    acc[1] = __builtin_amdgcn_mfma_f32_16x16x32_bf16(a1, b11, acc[1], 0, 0, 0);
  }
  __builtin_amdgcn_s_barrier();   // all waves' reads complete before LDS reuse
}

// Prestage helpers (must match gemm64's addressing exactly)
DEV void pre_slotAB(const u16* xa, int ldx, int xcols, const u16* ha, int ldh,
                    const u16* wsrc, int ldw, int m0, int n0, int tid, char* sm,
                    int ks) {
  char* lB = sm; char* lA = sm + 32768;
  const int row = tid >> 3, uu = tid & 7;
  const int usw = uu ^ (row & 7);
  const int wv = tid >> 6;
  const int k0 = ks << 6;
  const u16* ga;
  if (k0 < xcols) ga = xa + (size_t)(m0 + row) * ldx + (k0 + usw * 8);
  else            ga = ha + (size_t)(m0 + row) * ldh + (k0 - xcols + usw * 8);
  const u16* gb = wsrc + (size_t)(n0 + row) * ldw + (k0 + usw * 8);
  gll16(ga, lA + (wv << 10) + ((ks & 3) << 13));
  gll16(gb, lB + (wv << 10) + ((ks & 3) << 13));
}
DEV void pre_slotB(const u16* wsrc, int ldw, int n0, int tid, char* sm, int ks) {
  char* lB = sm;
  const int row = tid >> 3, uu = tid & 7;
  const int usw = uu ^ (row & 7);
  const int wv = tid >> 6;
  const int k0 = ks << 6;
  const u16* gb = wsrc + (size_t)(n0 + row) * ldw + (k0 + usw * 8);
  gll16(gb, lB + (wv << 10) + ((ks & 3) << 13));
}

// ----------------- LSTM pointwise epilogue, c in registers -----------------
// Overlay region: sm+49152 .. sm+65536 ([64][64] f32, exactly 16K).
DEV void lstm_ep_reg(const f32x4_t acc[2], int tid, char* sm,
                     const float* __restrict__ bias, float cc[2],
                     u16* __restrict__ hw, float* __restrict__ cpub,
                     int m0, int n0) {
  float* gl = (float*)(sm + 49152);
  const int l = tid & 63, l15 = l & 15, lhi = l >> 4;
  const int wv = tid >> 6, wr = wv >> 1, wc = wv & 1;
#pragma unroll
  for (int j = 0; j < 2; ++j)
#pragma unroll
    for (int qq = 0; qq < 4; ++qq)
      gl[(wr * 16 + lhi * 4 + qq) * 64 + wc * 32 + j * 16 + l15] = acc[j][qq];
  __syncthreads();
#pragma unroll
  for (int it = 0; it < 2; ++it) {
    int idx = it * 512 + tid;           // 1024 items: 64 rows x 16 j
    int r = idx >> 4, jj = idx & 15;
    f32x4_t g4 = *(const f32x4_t*)(gl + r * 64 + jj * 4);
    f32x4_t b4 = *(const f32x4_t*)(bias + n0 + jj * 4);
    float ig = sigm(g4[0] + b4[0]);
    float fg = sigm(g4[1] + b4[1]);
    float g_ = tanhf(g4[2] + b4[2]);
    float og = sigm(g4[3] + b4[3]);
    float cn = fg * cc[it] + ig * g_;
    cc[it] = cn;
    float hn = og * tanhf(cn);
    size_t off = (size_t)(m0 + r) * 1024 + (n0 >> 2) + jj;
    st_wt(&hw[off], f2b(hn));
    if (cpub) st_wt(&cpub[off], cn);
  }
  __syncthreads();
}

DEV void wx_store(const f32x4_t acc[2], int tid, u16* __restrict__ Wdec,
                  int m0, int n0) {
  const int l = tid & 63, l15 = l & 15, lhi = l >> 4;
  const int wv = tid >> 6, wr = wv >> 1, wc = wv & 1;
#pragma unroll
  for (int j = 0; j < 2; ++j)
#pragma unroll
    for (int qq = 0; qq < 4; ++qq) {
      int r = m0 + wr * 16 + lhi * 4 + qq;
      int c = n0 + wc * 32 + j * 16 + l15;
      st_wt(&Wdec[(size_t)r * 2048 + c], f2b(acc[j][qq]));
    }
}

// ------------------- phase 0: ToFeature (block-cooperative) ----------------
DEV void phase0_tf(const Params& p, int bid, int tid, char* sm) {
  float* xs = (float*)sm;            // [10][66]
  float* zs = (float*)(sm + 2688);   // [10][66]
  for (int g = tid; g < 660; g += NTHR) {
    int t = g / 66, q = g - t * 66;
    xs[g] = p.x[((size_t)bid * 10 + t) * 66 + q];
    zs[g] = p.z[((size_t)bid * 10 + t) * 66 + q];
  }
  __syncthreads();
  const int n = tid;                 // 512 feature outputs
  float accx[10], accz[10];
  float bn = p.tf_b[n];
#pragma unroll
  for (int t = 0; t < 10; ++t) { accx[t] = bn; accz[t] = bn; }
  const float* wrow = p.tf_w + (size_t)n * 66;
  for (int k = 0; k < 66; ++k) {
    float wk = wrow[k];
#pragma unroll
    for (int t = 0; t < 10; ++t) {
      accx[t] = fmaf(wk, xs[t * 66 + k], accx[t]);
      accz[t] = fmaf(wk, zs[t * 66 + k], accz[t]);
    }
  }
#pragma unroll
  for (int t = 0; t < 10; ++t) {
    p.xf[(size_t)t * 131072 + (size_t)bid * 512 + n] = f2b(accx[t]);
    p.zf[(size_t)t * 131072 + (size_t)bid * 512 + n] = f2b(accz[t]);
  }
  __syncthreads();
}

// --------------------------- phase 0a: conversions -------------------------
DEV void phase0a(const Params& p, int gtid) {
  for (int g = gtid; g < 786432; g += NT_ALL) {     // enc/encp 4096 x 192 units
    int row = g / 192;
    int u = g - row * 192;
    int k = u * 8;
    int nsrc = (row & 3) * 1024 + (row >> 2);       // gate-interleaved rows
    const float* s1 = (k < 512) ? (p.e_wih + (size_t)nsrc * 512 + k)
                                : (p.e_whh + (size_t)nsrc * 1024 + (k - 512));
    ((uint4*)p.Wenc)[g] = cvt8(s1);
    const float* s2 = (k < 512) ? (p.p_wih + (size_t)nsrc * 512 + k)
                                : (p.p_whh + (size_t)nsrc * 1024 + (k - 512));
    ((uint4*)p.Wencp)[g] = cvt8(s2);
  }
  for (int g = gtid; g < 524288; g += NT_ALL) {     // dec whh -> Wdec[:,1024:]
    int row = g >> 7, u = g & 127;
    int nsrc = (row & 3) * 1024 + (row >> 2);
    ((uint4*)p.Wdec)[row * 256 + 128 + u] = cvt8(p.d_whh + (size_t)nsrc * 1024 + u * 8);
  }
  for (int g = gtid; g < 262144; g += NT_ALL) {     // dec wih (gate-permuted)
    int row = g >> 6, u = g & 63;
    int nsrc = (row & 3) * 1024 + (row >> 2);
    ((uint4*)p.wihP)[g] = cvt8(p.d_wih + (size_t)nsrc * 512 + u * 8);
  }
  for (int g = gtid; g < 524288; g += NT_ALL) {     // lin_w transpose
    int f = g >> 10, h = g & 1023;
    p.linT[(size_t)h * 512 + f] = f2b(p.lin_w[g]);
  }
  for (int g = gtid; g < 8448; g += NT_ALL)
    ((uint4*)p.tpw)[g] = cvt8(p.tp_w + g * 8);
  for (int g = gtid; g < 4096; g += NT_ALL) {       // enc biases
    int nsrc = (g & 3) * 1024 + (g >> 2);
    p.bias_e[g]  = p.e_bih[nsrc] + p.e_bhh[nsrc];
    p.bias_ep[g] = p.p_bih[nsrc] + p.p_bhh[nsrc];
  }
  for (int g = gtid; g < 32768; g += NT_ALL) {      // bias_d partials (wih@lin_b)
    int cell = g >> 3, sub = g & 7;
    int nsrc = (cell & 3) * 1024 + (cell >> 2);
    const float* wr_ = p.d_wih + (size_t)nsrc * 512 + sub * 64;
    const float* lb = p.lin_b + sub * 64;
    float s = 0.f;
    for (int f = 0; f < 64; ++f) s += wr_[f] * lb[f];
    p.bias_part[g] = s;
  }
  uint4 zz; zz.x = zz.y = zz.z = zz.w = 0u;         // zero h0 for both encoders
  for (int g = gtid; g < 32768; g += NT_ALL) { ((uint4*)p.he)[g] = zz; ((uint4*)p.hp)[g] = zz; }
}

// --------------------------- attention (1 row / block) ---------------------
// LDS region: catl at sm+16384 (43008 B), cl at sm+59392 (4096 B), sc after.
// Keeps prestaged B slots 0,1 (sm[0..16384)) intact.
DEV void attention(const Params& p, const u16* hd_prev, const float* cpub,
                   u16* atth_s, int b, int tid, char* sm) {
  u16*   catl = (u16*)(sm + 16384);
  float* cl   = (float*)(sm + 59392);
  float* sc   = (float*)(sm + 63488);
  for (int g = tid; g < 2688; g += NTHR) {
    int t = g >> 7, hu = g & 127;
    const u16* src;
    if (t < 10)       src = p.he + (size_t)(t + 1) * HSTRIDE;
    else if (t == 10) src = hd_prev;
    else              src = p.hp + (size_t)(t - 10) * HSTRIDE;
    ((uint4*)catl)[g] = *(const uint4*)(src + (size_t)b * 1024 + hu * 8);
  }
  for (int g = tid; g < 512; g += NTHR) {
    unsigned long long v = ld_byp(((const unsigned long long*)(cpub + (size_t)b * 1024)) + g);
    ((unsigned long long*)cl)[g] = v;
  }
  __syncthreads();
  const int wv = tid >> 6, l = tid & 63;
  for (int t = wv; t < 21; t += 8) {
    float s = 0.f;
    const u16* cr = catl + t * 1024;
    for (int hh = l; hh < 1024; hh += 64) s += cl[hh] * b2f(cr[hh]);
#pragma unroll
    for (int o = 32; o; o >>= 1) s += __shfl_down(s, o);
    if (l == 0) sc[t] = s;
  }
  __syncthreads();
  float m = -1e30f;
#pragma unroll
  for (int t = 0; t < 21; ++t) m = fmaxf(m, sc[t]);
  float e[21]; float den = 0.f;
#pragma unroll
  for (int t = 0; t < 21; ++t) { e[t] = __expf(sc[t] - m); den += e[t]; }
  float inv = 1.0f / den;
  const int h0 = tid * 2;
  float a0 = 0.f, a1 = 0.f;
#pragma unroll
  for (int t = 0; t < 21; ++t) {
    float w_ = e[t] * inv;
    unsigned v = *(const unsigned*)(catl + t * 1024 + h0);
    a0 += w_ * b2f((u16)(v & 0xffff));
    a1 += w_ * b2f((u16)(v >> 16));
  }
  st_wt(((unsigned*)(atth_s + (size_t)b * 1024)) + tid, pk2(a0, a1));
  __syncthreads();   // catl reads done before gemm1 stages into this region
}

// ------------------------- final projection (1 b / block) ------------------
DEV void finalproj(const Params& p, int b, int tid, char* sm) {
  u16* hl = (u16*)sm;                     // [25][1024] bf16 = 51200 B
  for (int g = tid; g < 3200; g += NTHR) {
    int t = g >> 7, hu = g & 127;
    ((uint4*)hl)[g] = *(const uint4*)(p.hs + ((size_t)(t * 256 + b)) * 1024 + hu * 8);
  }
  __syncthreads();
  if (tid < 330) {
    int pcol = tid % 66, tg = tid / 66;   // 5 groups of 5 timesteps
    float acc[5] = {0.f, 0.f, 0.f, 0.f, 0.f};
    const u16* wrow = p.tpw + (size_t)pcol * 1024;
    for (int hc = 0; hc < 128; ++hc) {
      uint4 wv4 = ((const uint4*)wrow)[hc];
      float wf[8];
      wf[0] = b2f(wv4.x & 0xffff); wf[1] = b2f(wv4.x >> 16);
      wf[2] = b2f(wv4.y & 0xffff); wf[3] = b2f(wv4.y >> 16);
      wf[4] = b2f(wv4.z & 0xffff); wf[5] = b2f(wv4.z >> 16);
      wf[6] = b2f(wv4.w & 0xffff); wf[7] = b2f(wv4.w >> 16);
#pragma unroll
      for (int r = 0; r < 5; ++r) {
        int t = tg * 5 + r;
        uint4 hv = ((const uint4*)(hl + t * 1024))[hc];
        float s;
        s  = wf[0] * b2f(hv.x & 0xffff) + wf[1] * b2f(hv.x >> 16);
        s += wf[2] * b2f(hv.y & 0xffff) + wf[3] * b2f(hv.y >> 16);
        s += wf[4] * b2f(hv.z & 0xffff) + wf[5] * b2f(hv.z >> 16);
        s += wf[6] * b2f(hv.w & 0xffff) + wf[7] * b2f(hv.w >> 16);
        acc[r] += s;
      }
    }
    float bb = p.tp_b[pcol];
#pragma unroll
    for (int r = 0; r < 5; ++r) {
      int t = tg * 5 + r;
      size_t o = (size_t)b * 1650 + (size_t)t * 66 + pcol;
      p.out[o] = acc[r] + bb + p.resid[o];
    }
  }
}

// ------------------------------- main kernel -------------------------------
__global__ __launch_bounds__(NTHR) void model_kernel(Params p) {
  cg::grid_group gg = cg::this_grid();
  __shared__ __align__(16) char sm[65536];
  const int tid = threadIdx.x;
  const int bid = blockIdx.x;
  const int gtid = bid * NTHR + tid;

  phase0_tf(p, bid, tid, sm);
  phase0a(p, gtid);
  if (bid == 0 && tid < 16) st_wt(&p.bar[tid * 16], 0u);   // reset all counters
  gg.sync();                      // ONLY full-fence sync (flushes phase0 writes)

  // P0b: finalize bias_d; Wdec[:,0:1024] = (gate-permuted dec_wih) @ lin_w
  for (int g = gtid; g < 4096; g += NT_ALL) {
    int nsrc = (g & 3) * 1024 + (g >> 2);
    float s = p.d_bih[nsrc] + p.d_bhh[nsrc];
#pragma unroll
    for (int k8 = 0; k8 < 8; ++k8) s += p.bias_part[g * 8 + k8];
    st_wt(&p.bias_d[g], s);
  }
#pragma unroll 1
  for (int i = 0; i < 4; ++i) {
    int tt = bid * 4 + i;
    int m0w = (tt & 63) << 6;
    int n0w = (tt >> 6) << 6;
    f32x4_t acc[2]; acc[0] = fzero4(); acc[1] = fzero4();
    gemm64<0>(p.wihP, 512, 512, p.wihP, 0, p.linT, 512, 512, m0w, n0w, tid, sm, acc);
    wx_store(acc, tid, p.Wdec, m0w, n0w);
  }

  // Lane geometry: lane = batch group (m), j = n-tile; j&7 = XCD weight slice.
  const int lane = bid >> 6, j = bid & 63;
  const int m0 = lane << 6;
  const int n0 = ((j & 7) * 8 + (j >> 3)) << 6;
  const int b = (lane << 6) + j;   // attention / finalproj batch row

  // Prestage encoder step 0 (xf + Wenc are ready), then global barrier.
  pre_slotAB(p.xf, 512, 512, p.he, 1024, p.Wenc, 1536, m0, n0, tid, sm, 0);
  pre_slotAB(p.xf, 512, 512, p.he, 1024, p.Wenc, 1536, m0, n0, tid, sm, 1);
  gridbar(p.bar, 1, tid, bid);

  float ce[2] = {0.f, 0.f}, cp[2] = {0.f, 0.f};   // c in registers, all steps
  unsigned lep = 0;

  // P1: both encoders, 10 steps
#pragma unroll 1
  for (int t = 0; t < 10; ++t) {
    f32x4_t acc[2]; acc[0] = fzero4(); acc[1] = fzero4();
    gemm64<1>(p.xf + (size_t)t * 131072, 512, 512, p.he + (size_t)t * HSTRIDE, 1024,
              p.Wenc, 1536, 1536, m0, n0, tid, sm, acc);
    // prestage encp (zf + Wencp static) while epilogue runs
    pre_slotAB(p.zf + (size_t)t * 131072, 512, 512, p.hp, 1024, p.Wencp, 1536, m0, n0, tid, sm, 0);
    pre_slotAB(p.zf + (size_t)t * 131072, 512, 512, p.hp, 1024, p.Wencp, 1536, m0, n0, tid, sm, 1);
    lstm_ep_reg(acc, tid, sm, p.bias_e, ce, p.he + (size_t)(t + 1) * HSTRIDE,
                (t == 9) ? p.c_pub : (float*)0, m0, n0);
    acc[0] = fzero4(); acc[1] = fzero4();
    gemm64<1>(p.zf + (size_t)t * 131072, 512, 512, p.hp + (size_t)t * HSTRIDE, 1024,
              p.Wencp, 1536, 1536, m0, n0, tid, sm, acc);
    if (t < 9) {   // prestage next encoder step (xf[t+1] + Wenc static)
      pre_slotAB(p.xf + (size_t)(t + 1) * 131072, 512, 512, p.he, 1024, p.Wenc, 1536, m0, n0, tid, sm, 0);
      pre_slotAB(p.xf + (size_t)(t + 1) * 131072, 512, 512, p.he, 1024, p.Wenc, 1536, m0, n0, tid, sm, 1);
    } else {       // prestage decoder gemm1 B (Wdec first K-half)
      pre_slotB(p.Wdec, 2048, n0, tid, sm, 0);
      pre_slotB(p.Wdec, 2048, n0, tid, sm, 1);
    }
    lstm_ep_reg(acc, tid, sm, p.bias_ep, cp, p.hp + (size_t)(t + 1) * HSTRIDE,
                (float*)0, m0, n0);
    ++lep; lanebar(p.bar, lep, lane, j, tid);
  }

  // P3: decoder, 25 steps. c continues in ce[]; h_dec[0] aliases he[10].
#pragma unroll 1
  for (int s = 0; s < 25; ++s) {
    const u16* hd_prev = (s == 0) ? (p.he + (size_t)10 * HSTRIDE)
                                  : (p.hs + (size_t)(s - 1) * HSTRIDE);
    u16* atth_s = p.atth + (size_t)s * HSTRIDE;
    attention(p, hd_prev, p.c_pub + (size_t)(s & 1) * 262144, atth_s, b, tid, sm);
    // gemm half 1: gates += hd_prev @ Wdec[:, 0:1024]   (no atth dependency)
    f32x4_t acc[2]; acc[0] = fzero4(); acc[1] = fzero4();
    gemm64<2>(hd_prev, 1024, 1024, hd_prev, 1024, p.Wdec, 2048, 1024,
              m0, n0, tid, sm, acc);
    pre_slotB(p.Wdec + 1024, 2048, n0, tid, sm, 0);   // B for gemm half 2
    pre_slotB(p.Wdec + 1024, 2048, n0, tid, sm, 1);
    ++lep; lanebar(p.bar, lep, lane, j, tid);
    // gemm half 2: gates += atth @ Wdec[:, 1024:2048]
    gemm64<2>(atth_s, 1024, 1024, atth_s, 1024, p.Wdec + 1024, 2048, 1024,
              m0, n0, tid, sm, acc);
    lstm_ep_reg(acc, tid, sm, p.bias_d, ce, p.hs + (size_t)s * HSTRIDE,
                p.c_pub + (size_t)((s + 1) & 1) * 262144, m0, n0);
    if (s < 24) {   // B for next step's gemm half 1
      pre_slotB(p.Wdec, 2048, n0, tid, sm, 0);
      pre_slotB(p.Wdec, 2048, n0, tid, sm, 1);
    }
    ++lep; lanebar(p.bar, lep, lane, j, tid);
  }

  // P4: out = dec_h @ tp_w.T + tp_b + for_resid
  finalproj(p, b, tid, sm);
}

// ------------------------------- host launch -------------------------------
extern "C" void kernel_launch(void* const* d_in, const int* in_sizes, int n_in,
                              void* d_out, int out_size, void* d_ws, size_t ws_size,
                              hipStream_t stream) {
  (void)in_sizes; (void)n_in; (void)out_size;
  Params P;
  P.x     = (const float*)d_in[0];
  P.z     = (const float*)d_in[1];
  P.resid = (const float*)d_in[2];
  P.tf_w  = (const float*)d_in[3];
  P.tf_b  = (const float*)d_in[4];
  P.e_wih = (const float*)d_in[5];
  P.e_whh = (const float*)d_in[6];
  P.e_bih = (const float*)d_in[7];
  P.e_bhh = (const float*)d_in[8];
  P.p_wih = (const float*)d_in[9];
  P.p_whh = (const float*)d_in[10];
  P.p_bih = (const float*)d_in[11];
  P.p_bhh = (const float*)d_in[12];
  P.d_wih = (const float*)d_in[13];
  P.d_whh = (const float*)d_in[14];
  P.d_bih = (const float*)d_in[15];
  P.d_bhh = (const float*)d_in[16];
  P.lin_w = (const float*)d_in[17];
  P.lin_b = (const float*)d_in[18];
  P.tp_w  = (const float*)d_in[19];
  P.tp_b  = (const float*)d_in[20];

  char* w = (char*)d_ws;
  size_t o = 0;
  auto take = [&](size_t bytes) { char* r = w + o; o = (o + bytes + 255) & ~(size_t)255; return r; };
  P.Wenc  = (u16*)take(4096ull * 1536 * 2);
  P.Wencp = (u16*)take(4096ull * 1536 * 2);
  P.Wdec  = (u16*)take(4096ull * 2048 * 2);
  P.wihP  = (u16*)take(4096ull * 512 * 2);
  P.linT  = (u16*)take(1024ull * 512 * 2);
  P.tpw   = (u16*)take(66ull * 1024 * 2);
  P.bias_e    = (float*)take(4096 * 4);
  P.bias_ep   = (float*)take(4096 * 4);
  P.bias_d    = (float*)take(4096 * 4);
  P.bias_part = (float*)take(32768 * 4);
  P.xf  = (u16*)take(10ull * 256 * 512 * 2);
  P.zf  = (u16*)take(10ull * 256 * 512 * 2);
  P.he  = (u16*)take(11ull * 256 * 1024 * 2);
  P.hp  = (u16*)take(11ull * 256 * 1024 * 2);
  P.hs  = (u16*)take(25ull * 256 * 1024 * 2);
  P.atth = (u16*)take(25ull * 256 * 1024 * 2);
  P.c_pub = (float*)take(2ull * 256 * 1024 * 4);
  P.bar = (unsigned*)take(16 * 64);
  P.out = (float*)d_out;

  if (o > ws_size) return;  // workspace too small: fail cleanly, no corruption

  void* args[] = { &P };
  hipLaunchCooperativeKernel((const void*)model_kernel, dim3(NBLK, 1, 1),
                             dim3(NTHR, 1, 1), args, 0, stream);
}